// Round 10
// baseline (250.747 us; speedup 1.0000x reference)
//
#include <hip/hip_runtime.h>
#include <cstdint>

typedef _Float16 f16;
typedef _Float16 f16x8 __attribute__((ext_vector_type(8)));
typedef _Float16 f16x4 __attribute__((ext_vector_type(4)));
typedef _Float16 f16x2 __attribute__((ext_vector_type(2)));
typedef float    f32x4 __attribute__((ext_vector_type(4)));
typedef float    f32x16 __attribute__((ext_vector_type(16)));
typedef unsigned int uint;
typedef uint     uintx2 __attribute__((ext_vector_type(2)));

#define NB   8
#define SEQL 1024
#define EMB  1024
#define NH   16
#define HD   64
#define MR   (NB*SEQL)                        /* 8192 rows */
#define BHND ((size_t)NB*NH*SEQL*HD)          /* 8388608 elems per q/k/v buf */

// ---------------- async global->LDS (16B) ----------------------------------
static __device__ __forceinline__ void gload16(const void* g, void* l) {
  __builtin_amdgcn_global_load_lds(
      (const __attribute__((address_space(1))) char*)(uintptr_t)g,
      (__attribute__((address_space(3))) char*)(uintptr_t)l,
      16, 0, 0);
}

static __device__ __forceinline__ uint packf16(float a, float b) {
  f16x2 h; h[0] = (f16)a; h[1] = (f16)b;
  return __builtin_bit_cast(uint, h);
}

// ---------------- fp32 -> fp16 convert -------------------------------------
__global__ __launch_bounds__(256) void cvt_f32_f16(const float* __restrict__ src,
                                                   f16* __restrict__ dst, int n4) {
  int i = blockIdx.x * 256 + threadIdx.x;
  if (i >= n4) return;
  float4 v = ((const float4*)src)[i];
  f16x4 h;
  h[0] = (f16)v.x; h[1] = (f16)v.y; h[2] = (f16)v.z; h[3] = (f16)v.w;
  *(f16x4*)(dst + (size_t)i * 4) = h;
}

// ---------------- GEMM C = A[M,1024] * Bt[NTOT,1024]^T + bias ---------------
template<int NTOT, int MODE>
__global__ __launch_bounds__(256, 2) void gemm_bt(const f16* __restrict__ A,
                                                  const f16* __restrict__ Bt,
                                                  const float* __restrict__ bias,
                                                  void* __restrict__ outp) {
  __shared__ char smem[32768];
  const int t = threadIdx.x;
  const int w = t >> 6, lane = t & 63;
  const int lg = lane >> 4, lc = lane & 15;
  const int m0 = blockIdx.x * 128;
  const int n0 = blockIdx.y * 128;
  const int wr = w >> 1, wc = w & 1;

  f32x4 acc[4][4];
#pragma unroll
  for (int i = 0; i < 4; ++i)
#pragma unroll
    for (int j = 0; j < 4; ++j) acc[i][j] = (f32x4){0.f, 0.f, 0.f, 0.f};

  const char* Ab = (const char*)A + (size_t)m0 * 2048;
  const char* Bb = (const char*)Bt + (size_t)n0 * 2048;

  for (int k0 = 0; k0 < 1024; k0 += 64) {
#pragma unroll
    for (int f = 0; f < 4; ++f) {
      const int ci = f * 4 + w;
      const int x = ci * 1024 + lane * 16;
      const int row = x >> 7;
      const int col = (x & 127) ^ ((row & 7) << 4);
      gload16(Ab + (size_t)row * 2048 + k0 * 2 + col, smem + ci * 1024);
      gload16(Bb + (size_t)row * 2048 + k0 * 2 + col, smem + 16384 + ci * 1024);
    }
    __syncthreads();

#pragma unroll
    for (int kk = 0; kk < 2; ++kk) {
      f16x8 af[4], bf[4];
#pragma unroll
      for (int i = 0; i < 4; ++i) {
        const int ra = wr * 64 + i * 16 + lc;
        int ba = ra * 128 + kk * 64 + lg * 16;
        ba ^= (ra & 7) << 4;
        af[i] = *(const f16x8*)(smem + ba);
        const int rb = wc * 64 + i * 16 + lc;
        int bb = rb * 128 + kk * 64 + lg * 16;
        bb ^= (rb & 7) << 4;
        bf[i] = *(const f16x8*)(smem + 16384 + bb);
      }
#pragma unroll
      for (int i = 0; i < 4; ++i)
#pragma unroll
        for (int j = 0; j < 4; ++j)
          acc[i][j] = __builtin_amdgcn_mfma_f32_16x16x32_f16(af[i], bf[j], acc[i][j], 0, 0, 0);
    }
    __syncthreads();
  }

  float biasv[4];
#pragma unroll
  for (int j = 0; j < 4; ++j) biasv[j] = bias[n0 + wc * 64 + j * 16 + lc];

  if (MODE == 1) {
    float* Out = (float*)outp;
#pragma unroll
    for (int i = 0; i < 4; ++i)
#pragma unroll
      for (int j = 0; j < 4; ++j) {
        const int colL = n0 + wc * 64 + j * 16 + lc;
#pragma unroll
        for (int r = 0; r < 4; ++r) {
          const int row = m0 + wr * 64 + i * 16 + lg * 4 + r;
          Out[(size_t)row * NTOT + colL] = acc[i][j][r] + biasv[j];
        }
      }
  } else {
    f16* qkv = (f16*)outp;
#pragma unroll
    for (int i = 0; i < 4; ++i) {
      const int rbase = m0 + wr * 64 + i * 16 + lg * 4;
#pragma unroll
      for (int j = 0; j < 4; ++j) {
        const int colL = n0 + wc * 64 + j * 16 + lc;
        const int which = colL >> 10;
        const int e = colL & 1023;
        const int h = e >> 6, d = e & 63;
#pragma unroll
        for (int r = 0; r < 4; ++r) {
          const int rr = rbase + r;
          const int b = rr >> 10, n = rr & 1023;
          qkv[(size_t)which * BHND + ((size_t)(b * NH + h) * SEQL + n) * HD + d] =
              (f16)(acc[i][j][r] + biasv[j]);
        }
      }
    }
  }
}

// ---------------- V [b][h][n][d] -> Vt [b][h][d][n] -------------------------
__global__ __launch_bounds__(256) void transpose_v(const f16* __restrict__ V,
                                                   f16* __restrict__ Vt) {
  __shared__ f16 tile[64 * 72];
  const int bid = blockIdx.x;
  const int bh = bid >> 4, nt = bid & 15;
  const int t = threadIdx.x;
  const int r = t >> 2, c0 = (t & 3) * 16;
  const f16* src = V + ((size_t)bh * SEQL + nt * 64 + r) * HD + c0;
  f16x8 a0 = *(const f16x8*)src;
  f16x8 a1 = *(const f16x8*)(src + 8);
#pragma unroll
  for (int e = 0; e < 8; ++e) {
    tile[(c0 + e) * 72 + r] = a0[e];
    tile[(c0 + 8 + e) * 72 + r] = a1[e];
  }
  __syncthreads();
  f16* dst = Vt + ((size_t)bh * HD + r) * SEQL + nt * 64 + c0;
  *(f16x8*)dst = *(const f16x8*)&tile[r * 72 + c0];
  *(f16x8*)(dst + 8) = *(const f16x8*)&tile[r * 72 + c0 + 8];
}

// ---------------- flash attention, swapped 32x32x16 MFMA --------------------
// grid: 1024; decode bh = bid&127, qb = bid>>7 so all 8 q-blocks of one head
// land on the same XCD (bid%8 == bh%8) -> K/V L2-resident per XCD.
// S^T = mfma(K, Q): lane owns q = lane&31 (stats lane-local)
// O^T = mfma(Vt, P^T): acc col = q = lane&31 (rescale lane-local)
__global__ __launch_bounds__(256, 2) void attn_fwd(const f16* __restrict__ Q,
                                                   const f16* __restrict__ Kh,
                                                   const f16* __restrict__ Vt,
                                                   f16* __restrict__ Oh) {
  __shared__ uint4 Kl4[512];   // 8 KB: K tile [n=64][d=64] f16, XOR-swizzled
  __shared__ uint4 Vl4[512];   // 8 KB: Vt tile [d=64][n=64] f16, XOR-swizzled
  char* Kl = (char*)Kl4;
  char* Vl = (char*)Vl4;

  const int bid = blockIdx.x;
  const int bh = bid & 127;          // b*NH + h  (XCD-local: bid%8 == bh%8)
  const int qb = bid >> 7;
  const int t = threadIdx.x;
  const int w = t >> 6, lane = t & 63;
  const int l31 = lane & 31, hi = lane >> 5;

  const char* kbp = (const char*)Kh + (size_t)bh * 131072;   // SEQL*HD*2 bytes
  const char* vbp = (const char*)Vt + (size_t)bh * 131072;

  // Q fragment (B-operand of S^T): B[d][q]: col=q=l31, k=d = dc*16 + hi*8 + j
  const f16* qp = Q + ((size_t)bh * SEQL + qb * 128 + w * 32 + l31) * HD;
  f16x8 qf[4];
#pragma unroll
  for (int dc = 0; dc < 4; ++dc) {
    f16x8 v = *(const f16x8*)(qp + dc * 16 + hi * 8);
#pragma unroll
    for (int e = 0; e < 8; ++e) v[e] = v[e] * (f16)0.125f;
    qf[dc] = v;
  }

  f32x16 acc0, acc1;
#pragma unroll
  for (int i = 0; i < 16; ++i) { acc0[i] = 0.f; acc1[i] = 0.f; }
  float m = -1e30f, l = 0.f;

  for (int kt = 0; kt < 16; ++kt) {
    // ---- stage K and Vt tiles (16 KB total, 4 gload16 per wave) ----
#pragma unroll
    for (int f = 0; f < 2; ++f) {
      const int ci = w * 2 + f;                 // wave-uniform chunk (1 KB)
      const int x = ci * 1024 + lane * 16;      // linear byte in tile
      const int row = x >> 7;                   // 128 B per tile-row
      const int col = (x & 127) ^ ((row & 7) << 4);   // inverse-swizzled source
      gload16(kbp + (size_t)(kt * 64 + row) * 128 + col, Kl + ci * 1024);
      gload16(vbp + (size_t)row * 2048 + kt * 128 + col, Vl + ci * 1024);
    }
    __syncthreads();

    // ---- S^T = K · Q : C col = q = l31, row = k over regs ----
    f32x16 s0, s1;
#pragma unroll
    for (int i = 0; i < 16; ++i) { s0[i] = 0.f; s1[i] = 0.f; }
#pragma unroll
    for (int dc = 0; dc < 4; ++dc) {
      const int cb = dc * 32 + hi * 16;
      const int a0 = (l31 * 128 + cb) ^ ((l31 & 7) << 4);
      const int a1 = ((l31 + 32) * 128 + cb) ^ ((l31 & 7) << 4);
      f16x8 kf0 = *(const f16x8*)(Kl + a0);
      f16x8 kf1 = *(const f16x8*)(Kl + a1);
      s0 = __builtin_amdgcn_mfma_f32_32x32x16_f16(kf0, qf[dc], s0, 0, 0, 0);
      s1 = __builtin_amdgcn_mfma_f32_32x32x16_f16(kf1, qf[dc], s1, 0, 0, 0);
    }

    // ---- lane-local online softmax (k = (reg&3)+8*(reg>>2)+4*hi + 32*ksub) ----
    float v[32];
#pragma unroll
    for (int i = 0; i < 16; ++i) { v[i] = s0[i]; v[16 + i] = s1[i]; }
#pragma unroll
    for (int st = 16; st >= 1; st >>= 1)
#pragma unroll
      for (int i = 0; i < st; ++i) v[i] = fmaxf(v[i], v[i + st]);
    const float mx = fmaxf(v[0], __shfl_xor(v[0], 32));

    // defer-max (T13): only rescale when any lane's max grew past THR=8
    if (__any(mx > m + 8.f)) {
      const float nm = fmaxf(m, mx);
      const float al = __expf(m - nm);
      m = nm;
      l *= al;
      acc0 *= al;
      acc1 *= al;
    }

    float p[32];
#pragma unroll
    for (int i = 0; i < 16; ++i) {
      p[i] = __expf(s0[i] - m);
      p[16 + i] = __expf(s1[i] - m);
    }
    float ts[32];
#pragma unroll
    for (int i = 0; i < 32; ++i) ts[i] = p[i];
#pragma unroll
    for (int st = 16; st >= 1; st >>= 1)
#pragma unroll
      for (int i = 0; i < st; ++i) ts[i] += ts[i + st];
    const float rs = ts[0] + __shfl_xor(ts[0], 32);
    l += rs;

    // ---- pack P to f16 pairs (B-fragment via permlane32_swap, T12) ----
    uint wk[16];
#pragma unroll
    for (int i = 0; i < 16; ++i) wk[i] = packf16(p[2 * i], p[2 * i + 1]);

    // ---- O^T += Vt · P^T ----
#pragma unroll
    for (int ksub = 0; ksub < 2; ++ksub)
#pragma unroll
      for (int kh = 0; kh < 2; ++kh) {
        const int b0 = ksub * 8 + kh * 4;
        // swap(a,b): r[0] = {lo: a, hi: b-from-lo-half}; r[1] = {lo: a-from-hi-half, hi: b}
        uintx2 r02 = __builtin_amdgcn_permlane32_swap(wk[b0 + 0], wk[b0 + 2], false, false);
        uintx2 r13 = __builtin_amdgcn_permlane32_swap(wk[b0 + 1], wk[b0 + 3], false, false);
        union { uint u[4]; f16x8 v; } fb;
        fb.u[0] = r02[0];
        fb.u[1] = r13[0];
        fb.u[2] = r02[1];
        fb.u[3] = r13[1];
        const int cb = ksub * 64 + kh * 32 + hi * 16;
        const int av0 = (l31 * 128 + cb) ^ ((l31 & 7) << 4);
        const int av1 = ((l31 + 32) * 128 + cb) ^ ((l31 & 7) << 4);
        f16x8 vf0 = *(const f16x8*)(Vl + av0);
        f16x8 vf1 = *(const f16x8*)(Vl + av1);
        acc0 = __builtin_amdgcn_mfma_f32_32x32x16_f16(vf0, fb.v, acc0, 0, 0, 0);
        acc1 = __builtin_amdgcn_mfma_f32_32x32x16_f16(vf1, fb.v, acc1, 0, 0, 0);
      }
    __syncthreads();
  }

  // ---- epilogue: O row = q (lane-local l), d = (r&3)+8*(r>>2)+4*hi+32*dsub ----
  const int b = bh >> 4, h = bh & 15;
  const float inv = 1.f / l;
  f16* ob = Oh + ((size_t)(b * SEQL) + qb * 128 + w * 32 + l31) * EMB + h * 64;
#pragma unroll
  for (int g = 0; g < 4; ++g) {
    f16x4 o0, o1;
#pragma unroll
    for (int e = 0; e < 4; ++e) {
      o0[e] = (f16)(acc0[g * 4 + e] * inv);
      o1[e] = (f16)(acc1[g * 4 + e] * inv);
    }
    *(f16x4*)(ob + g * 8 + hi * 4) = o0;
    *(f16x4*)(ob + 32 + g * 8 + hi * 4) = o1;
  }
}

// ---------------- launcher --------------------------------------------------
extern "C" void kernel_launch(void* const* d_in, const int* in_sizes, int n_in,
                              void* d_out, int out_size, void* d_ws, size_t ws_size,
                              hipStream_t stream) {
  (void)in_sizes; (void)n_in; (void)out_size; (void)ws_size;
  const float* x      = (const float*)d_in[0];
  const float* w_qkv  = (const float*)d_in[1];
  const float* b_qkv  = (const float*)d_in[2];
  const float* w_proj = (const float*)d_in[3];
  const float* b_proj = (const float*)d_in[4];
  char* ws = (char*)d_ws;

  // workspace layout (72 MB total, with aliasing)
  const size_t XH = 0;                  // x fp16            16 MB (dead after gemm1)
  const size_t WQ = 16777216;           // w_qkv fp16         6 MB
  const size_t WP = 23068672;           // w_proj fp16        2 MB
  const size_t QH = 25165824;           // q [b][h][n][d]    16 MB
  const size_t KH = 41943040;           // k [b][h][n][d]    16 MB
  const size_t VH = 58720256;           // v [b][h][n][d]    16 MB (dead after transpose)
  const size_t VT = 0;                  // v^T [b][h][d][n]  16 MB (aliases XH)
  const size_t AH = VH;                 // attn out [b][n][e] (aliases VH)

  f16* xh  = (f16*)(ws + XH);
  f16* wqh = (f16*)(ws + WQ);
  f16* wph = (f16*)(ws + WP);

  cvt_f32_f16<<<(MR * EMB / 4 + 255) / 256, 256, 0, stream>>>(x, xh, MR * EMB / 4);
  cvt_f32_f16<<<(3 * EMB * EMB / 4 + 255) / 256, 256, 0, stream>>>(w_qkv, wqh, 3 * EMB * EMB / 4);
  cvt_f32_f16<<<(EMB * EMB / 4 + 255) / 256, 256, 0, stream>>>(w_proj, wph, EMB * EMB / 4);

  gemm_bt<3072, 0><<<dim3(64, 24), 256, 0, stream>>>(xh, wqh, b_qkv, (void*)(ws + QH));

  transpose_v<<<NB * NH * (SEQL / 64), 256, 0, stream>>>((const f16*)(ws + VH), (f16*)(ws + VT));

  attn_fwd<<<NB * NH * 8, 256, 0, stream>>>((const f16*)(ws + QH),
                                            (const f16*)(ws + KH),
                                            (const f16*)(ws + VT),
                                            (f16*)(ws + AH));

  gemm_bt<1024, 1><<<dim3(64, 8), 256, 0, stream>>>((const f16*)(ws + AH), wph, b_proj, d_out);
}

// Round 11
// 244.116 us; speedup vs baseline: 1.0272x; 1.0272x over previous
//
#include <hip/hip_runtime.h>
#include <cstdint>

typedef _Float16 f16;
typedef _Float16 f16x8 __attribute__((ext_vector_type(8)));
typedef _Float16 f16x4 __attribute__((ext_vector_type(4)));
typedef _Float16 f16x2 __attribute__((ext_vector_type(2)));
typedef float    f32x4 __attribute__((ext_vector_type(4)));
typedef float    f32x16 __attribute__((ext_vector_type(16)));
typedef unsigned int uint;
typedef uint     uintx2 __attribute__((ext_vector_type(2)));

#define NB   8
#define SEQL 1024
#define EMB  1024
#define NH   16
#define HD   64
#define MR   (NB*SEQL)                        /* 8192 rows */
#define BHND ((size_t)NB*NH*SEQL*HD)          /* 8388608 elems per q/k/v buf */

// ---------------- async global->LDS (16B) ----------------------------------
static __device__ __forceinline__ void gload16(const void* g, void* l) {
  __builtin_amdgcn_global_load_lds(
      (const __attribute__((address_space(1))) char*)(uintptr_t)g,
      (__attribute__((address_space(3))) char*)(uintptr_t)l,
      16, 0, 0);
}

static __device__ __forceinline__ uint packf16(float a, float b) {
  f16x2 h; h[0] = (f16)a; h[1] = (f16)b;
  return __builtin_bit_cast(uint, h);
}

// ---------------- fused fp32 -> fp16 convert (x, w_qkv, w_proj) -------------
// float4 index ranges: x [0,2097152), w_qkv [..,2883584), w_proj [..,3145728)
__global__ __launch_bounds__(256) void cvt_all(const float* __restrict__ x,
                                               const float* __restrict__ wq,
                                               const float* __restrict__ wp,
                                               f16* __restrict__ xh,
                                               f16* __restrict__ wqh,
                                               f16* __restrict__ wph) {
  const int i = blockIdx.x * 256 + threadIdx.x;
  const float* src; f16* dst; int j;
  if (i < 2097152)      { src = x;  dst = xh;  j = i; }
  else if (i < 2883584) { src = wq; dst = wqh; j = i - 2097152; }
  else                  { src = wp; dst = wph; j = i - 2883584; }
  float4 v = ((const float4*)src)[j];
  f16x4 h;
  h[0] = (f16)v.x; h[1] = (f16)v.y; h[2] = (f16)v.z; h[3] = (f16)v.w;
  *(f16x4*)(dst + (size_t)j * 4) = h;
}

// ---------------- GEMM C = A[M,1024] * Bt[NTOT,1024]^T + bias ---------------
// MODE 0: scatter q,k into [b][h][n][d] fp16 (outp); V third written DIRECTLY
//         transposed to vt [b][h][d][n] (outp2) -- replaces transpose_v kernel.
// MODE 1: C fp32 to outp ([row*NTOT + col])
template<int NTOT, int MODE>
__global__ __launch_bounds__(256, 2) void gemm_bt(const f16* __restrict__ A,
                                                  const f16* __restrict__ Bt,
                                                  const float* __restrict__ bias,
                                                  void* __restrict__ outp,
                                                  void* __restrict__ outp2) {
  __shared__ char smem[32768];
  const int t = threadIdx.x;
  const int w = t >> 6, lane = t & 63;
  const int lg = lane >> 4, lc = lane & 15;
  const int m0 = blockIdx.x * 128;
  const int n0 = blockIdx.y * 128;
  const int wr = w >> 1, wc = w & 1;

  f32x4 acc[4][4];
#pragma unroll
  for (int i = 0; i < 4; ++i)
#pragma unroll
    for (int j = 0; j < 4; ++j) acc[i][j] = (f32x4){0.f, 0.f, 0.f, 0.f};

  const char* Ab = (const char*)A + (size_t)m0 * 2048;
  const char* Bb = (const char*)Bt + (size_t)n0 * 2048;

  for (int k0 = 0; k0 < 1024; k0 += 64) {
#pragma unroll
    for (int f = 0; f < 4; ++f) {
      const int ci = f * 4 + w;
      const int x = ci * 1024 + lane * 16;
      const int row = x >> 7;
      const int col = (x & 127) ^ ((row & 7) << 4);
      gload16(Ab + (size_t)row * 2048 + k0 * 2 + col, smem + ci * 1024);
      gload16(Bb + (size_t)row * 2048 + k0 * 2 + col, smem + 16384 + ci * 1024);
    }
    __syncthreads();

#pragma unroll
    for (int kk = 0; kk < 2; ++kk) {
      f16x8 af[4], bf[4];
#pragma unroll
      for (int i = 0; i < 4; ++i) {
        const int ra = wr * 64 + i * 16 + lc;
        int ba = ra * 128 + kk * 64 + lg * 16;
        ba ^= (ra & 7) << 4;
        af[i] = *(const f16x8*)(smem + ba);
        const int rb = wc * 64 + i * 16 + lc;
        int bb = rb * 128 + kk * 64 + lg * 16;
        bb ^= (rb & 7) << 4;
        bf[i] = *(const f16x8*)(smem + 16384 + bb);
      }
#pragma unroll
      for (int i = 0; i < 4; ++i)
#pragma unroll
        for (int j = 0; j < 4; ++j)
          acc[i][j] = __builtin_amdgcn_mfma_f32_16x16x32_f16(af[i], bf[j], acc[i][j], 0, 0, 0);
    }
    __syncthreads();
  }

  float biasv[4];
#pragma unroll
  for (int j = 0; j < 4; ++j) biasv[j] = bias[n0 + wc * 64 + j * 16 + lc];

  if (MODE == 1) {
    float* Out = (float*)outp;
#pragma unroll
    for (int i = 0; i < 4; ++i)
#pragma unroll
      for (int j = 0; j < 4; ++j) {
        const int colL = n0 + wc * 64 + j * 16 + lc;
#pragma unroll
        for (int r = 0; r < 4; ++r) {
          const int row = m0 + wr * 64 + i * 16 + lg * 4 + r;
          Out[(size_t)row * NTOT + colL] = acc[i][j][r] + biasv[j];
        }
      }
  } else {
    f16* qk = (f16*)outp;     // q at +0, k at +BHND
    f16* vt = (f16*)outp2;    // [b][h][d][n]
#pragma unroll
    for (int i = 0; i < 4; ++i) {
      const int rbase = m0 + wr * 64 + i * 16 + lg * 4;
      const int bb = rbase >> 10, nb = rbase & 1023;   // 4 rows stay in one n-block
#pragma unroll
      for (int j = 0; j < 4; ++j) {
        const int colL = n0 + wc * 64 + j * 16 + lc;
        const int which = colL >> 10;                  // wave-uniform
        const int e = colL & 1023;
        const int h = e >> 6, d = e & 63;
        if (which == 2) {
          f16x4 vv;
#pragma unroll
          for (int r = 0; r < 4; ++r) vv[r] = (f16)(acc[i][j][r] + biasv[j]);
          *(f16x4*)(vt + ((size_t)(bb * NH + h) * HD + d) * SEQL + nb) = vv;
        } else {
#pragma unroll
          for (int r = 0; r < 4; ++r) {
            const int rr = rbase + r;
            const int b = rr >> 10, n = rr & 1023;
            qk[(size_t)which * BHND + ((size_t)(b * NH + h) * SEQL + n) * HD + d] =
                (f16)(acc[i][j][r] + biasv[j]);
          }
        }
      }
    }
  }
}

// ---------------- flash attention, swapped 32x32x16 MFMA --------------------
// grid 1024; bh = bid&127 (XCD-local), qb = bid>>7.
// Double-buffered K/V staging (T3 2-phase): issue tile t+1 loads before
// computing tile t; end-of-iter __syncthreads drains vmcnt.
// exp2-domain softmax: 0.125*log2e folded into Q fragment.
__global__ __launch_bounds__(256, 2) void attn_fwd(const f16* __restrict__ Q,
                                                   const f16* __restrict__ Kh,
                                                   const f16* __restrict__ Vt,
                                                   f16* __restrict__ Oh) {
  __shared__ uint4 lds4[2048];   // 32 KB: [buf][K 8KB | V 8KB]
  char* lds = (char*)lds4;

  const int bid = blockIdx.x;
  const int bh = bid & 127;
  const int qb = bid >> 7;
  const int t = threadIdx.x;
  const int w = t >> 6, lane = t & 63;
  const int l31 = lane & 31, hi = lane >> 5;

  const char* kbp = (const char*)Kh + (size_t)bh * 131072;
  const char* vbp = (const char*)Vt + (size_t)bh * 131072;

  // Q fragment (B-operand of S^T): col=q=l31, k=d = dc*16 + hi*8 + j
  // scale = 0.125 * log2(e): softmax runs in exp2 domain
  const f16* qp = Q + ((size_t)bh * SEQL + qb * 128 + w * 32 + l31) * HD;
  f16x8 qf[4];
#pragma unroll
  for (int dc = 0; dc < 4; ++dc) {
    f16x8 v = *(const f16x8*)(qp + dc * 16 + hi * 8);
#pragma unroll
    for (int e = 0; e < 8; ++e) v[e] = v[e] * (f16)0.18033688f;
    qf[dc] = v;
  }

  f32x16 acc0, acc1;
#pragma unroll
  for (int i = 0; i < 16; ++i) { acc0[i] = 0.f; acc1[i] = 0.f; }
  float m = -1e30f, l = 0.f;

  // stage(kt, buf): 4 gload16/wave; linear LDS dest, inverse-swizzled source
#define STAGE(ktile, buf)                                                      \
  {                                                                            \
    _Pragma("unroll")                                                          \
    for (int f = 0; f < 2; ++f) {                                              \
      const int ci = w * 2 + f;                                                \
      const int x = ci * 1024 + lane * 16;                                     \
      const int row = x >> 7;                                                  \
      const int col = (x & 127) ^ ((row & 7) << 4);                            \
      gload16(kbp + (size_t)((ktile) * 64 + row) * 128 + col,                  \
              lds + (buf) * 16384 + ci * 1024);                                \
      gload16(vbp + (size_t)row * 2048 + (ktile) * 128 + col,                  \
              lds + (buf) * 16384 + 8192 + ci * 1024);                         \
    }                                                                          \
  }

  STAGE(0, 0);
  __syncthreads();
  int cur = 0;

  for (int kt = 0; kt < 16; ++kt) {
    if (kt < 15) STAGE(kt + 1, cur ^ 1);     // async prefetch, lands at barrier

    const char* Kl = lds + cur * 16384;
    const char* Vl = Kl + 8192;

    // ---- S^T = K · Q ----
    f32x16 s0, s1;
#pragma unroll
    for (int i = 0; i < 16; ++i) { s0[i] = 0.f; s1[i] = 0.f; }
    __builtin_amdgcn_s_setprio(1);
#pragma unroll
    for (int dc = 0; dc < 4; ++dc) {
      const int cb = dc * 32 + hi * 16;
      const int a0 = (l31 * 128 + cb) ^ ((l31 & 7) << 4);
      const int a1 = ((l31 + 32) * 128 + cb) ^ ((l31 & 7) << 4);
      f16x8 kf0 = *(const f16x8*)(Kl + a0);
      f16x8 kf1 = *(const f16x8*)(Kl + a1);
      s0 = __builtin_amdgcn_mfma_f32_32x32x16_f16(kf0, qf[dc], s0, 0, 0, 0);
      s1 = __builtin_amdgcn_mfma_f32_32x32x16_f16(kf1, qf[dc], s1, 0, 0, 0);
    }
    __builtin_amdgcn_s_setprio(0);

    // ---- lane-local online softmax (exp2 domain) ----
    float v0 = fmaxf(s0[0], s1[0]), v1 = fmaxf(s0[1], s1[1]);
    float v2 = fmaxf(s0[2], s1[2]), v3 = fmaxf(s0[3], s1[3]);
#pragma unroll
    for (int i = 4; i < 16; i += 4) {
      v0 = fmaxf(v0, fmaxf(s0[i], s1[i]));
      v1 = fmaxf(v1, fmaxf(s0[i + 1], s1[i + 1]));
      v2 = fmaxf(v2, fmaxf(s0[i + 2], s1[i + 2]));
      v3 = fmaxf(v3, fmaxf(s0[i + 3], s1[i + 3]));
    }
    float mxl = fmaxf(fmaxf(v0, v1), fmaxf(v2, v3));
    const float mx = fmaxf(mxl, __shfl_xor(mxl, 32));

    // defer-max (T13), THR = 11.5 in log2 units (exp2(11.5) ~ 2896 < f16 max)
    if (__any(mx > m + 11.5f)) {
      const float nm = fmaxf(m, mx);
      const float al = __builtin_exp2f(m - nm);
      m = nm;
      l *= al;
      acc0 *= al;
      acc1 *= al;
    }

    float p[32];
#pragma unroll
    for (int i = 0; i < 16; ++i) {
      p[i] = __builtin_exp2f(s0[i] - m);
      p[16 + i] = __builtin_exp2f(s1[i] - m);
    }
    float t0 = 0.f, t1 = 0.f, t2 = 0.f, t3 = 0.f;
#pragma unroll
    for (int i = 0; i < 32; i += 4) {
      t0 += p[i]; t1 += p[i + 1]; t2 += p[i + 2]; t3 += p[i + 3];
    }
    const float rsl = (t0 + t1) + (t2 + t3);
    l += rsl + __shfl_xor(rsl, 32);

    // ---- pack P to f16 pairs ----
    uint wk[16];
#pragma unroll
    for (int i = 0; i < 16; ++i) wk[i] = packf16(p[2 * i], p[2 * i + 1]);

    // ---- O^T += Vt · P^T (B-fragment via permlane32_swap) ----
    __builtin_amdgcn_s_setprio(1);
#pragma unroll
    for (int ksub = 0; ksub < 2; ++ksub)
#pragma unroll
      for (int kh = 0; kh < 2; ++kh) {
        const int b0 = ksub * 8 + kh * 4;
        uintx2 r02 = __builtin_amdgcn_permlane32_swap(wk[b0 + 0], wk[b0 + 2], false, false);
        uintx2 r13 = __builtin_amdgcn_permlane32_swap(wk[b0 + 1], wk[b0 + 3], false, false);
        union { uint u[4]; f16x8 v; } fb;
        fb.u[0] = r02[0];
        fb.u[1] = r13[0];
        fb.u[2] = r02[1];
        fb.u[3] = r13[1];
        const int cb = ksub * 64 + kh * 32 + hi * 16;
        const int av0 = (l31 * 128 + cb) ^ ((l31 & 7) << 4);
        const int av1 = ((l31 + 32) * 128 + cb) ^ ((l31 & 7) << 4);
        f16x8 vf0 = *(const f16x8*)(Vl + av0);
        f16x8 vf1 = *(const f16x8*)(Vl + av1);
        acc0 = __builtin_amdgcn_mfma_f32_32x32x16_f16(vf0, fb.v, acc0, 0, 0, 0);
        acc1 = __builtin_amdgcn_mfma_f32_32x32x16_f16(vf1, fb.v, acc1, 0, 0, 0);
      }
    __builtin_amdgcn_s_setprio(0);

    __syncthreads();   // drains vmcnt (tile kt+1 ready) + lgkm; frees buf cur
    cur ^= 1;
  }
#undef STAGE

  // ---- epilogue ----
  const int b = bh >> 4, h = bh & 15;
  const float inv = 1.f / l;
  f16* ob = Oh + ((size_t)(b * SEQL) + qb * 128 + w * 32 + l31) * EMB + h * 64;
#pragma unroll
  for (int g = 0; g < 4; ++g) {
    f16x4 o0, o1;
#pragma unroll
    for (int e = 0; e < 4; ++e) {
      o0[e] = (f16)(acc0[g * 4 + e] * inv);
      o1[e] = (f16)(acc1[g * 4 + e] * inv);
    }
    *(f16x4*)(ob + g * 8 + hi * 4) = o0;
    *(f16x4*)(ob + 32 + g * 8 + hi * 4) = o1;
  }
}

// ---------------- launcher --------------------------------------------------
extern "C" void kernel_launch(void* const* d_in, const int* in_sizes, int n_in,
                              void* d_out, int out_size, void* d_ws, size_t ws_size,
                              hipStream_t stream) {
  (void)in_sizes; (void)n_in; (void)out_size; (void)ws_size;
  const float* x      = (const float*)d_in[0];
  const float* w_qkv  = (const float*)d_in[1];
  const float* b_qkv  = (const float*)d_in[2];
  const float* w_proj = (const float*)d_in[3];
  const float* b_proj = (const float*)d_in[4];
  char* ws = (char*)d_ws;

  // workspace layout (72 MB, aliasing):
  const size_t XH = 0;                  // x fp16            16 MB (dead after gemm1)
  const size_t WQ = 16777216;           // w_qkv fp16         6 MB
  const size_t WP = 23068672;           // w_proj fp16        2 MB
  const size_t QH = 25165824;           // q [b][h][n][d]    16 MB
  const size_t KH = 41943040;           // k [b][h][n][d]    16 MB (QH + BHND*2)
  const size_t VT = 58720256;           // v^T [b][h][d][n]  16 MB (written by gemm1)
  const size_t AH = 0;                  // attn out [b][n][e] fp16 (aliases dead XH)

  f16* xh  = (f16*)(ws + XH);
  f16* wqh = (f16*)(ws + WQ);
  f16* wph = (f16*)(ws + WP);

  cvt_all<<<12288, 256, 0, stream>>>(x, w_qkv, w_proj, xh, wqh, wph);

  gemm_bt<3072, 0><<<dim3(64, 24), 256, 0, stream>>>(xh, wqh, b_qkv,
                                                     (void*)(ws + QH), (void*)(ws + VT));

  attn_fwd<<<NB * NH * 8, 256, 0, stream>>>((const f16*)(ws + QH),
                                            (const f16*)(ws + KH),
                                            (const f16*)(ws + VT),
                                            (f16*)(ws + AH));

  gemm_bt<1024, 1><<<dim3(64, 8), 256, 0, stream>>>((const f16*)(ws + AH), wph, b_proj,
                                                    d_out, nullptr);
}

// Round 16
// 230.816 us; speedup vs baseline: 1.0863x; 1.0576x over previous
//
#include <hip/hip_runtime.h>
#include <cstdint>

typedef _Float16 f16;
typedef _Float16 f16x8 __attribute__((ext_vector_type(8)));
typedef _Float16 f16x4 __attribute__((ext_vector_type(4)));
typedef _Float16 f16x2 __attribute__((ext_vector_type(2)));
typedef float    f32x4 __attribute__((ext_vector_type(4)));
typedef float    f32x16 __attribute__((ext_vector_type(16)));
typedef unsigned int uint;
typedef uint     uintx2 __attribute__((ext_vector_type(2)));

#define NB   8
#define SEQL 1024
#define EMB  1024
#define NH   16
#define HD   64
#define MR   (NB*SEQL)                        /* 8192 rows */
#define BHND ((size_t)NB*NH*SEQL*HD)          /* 8388608 elems per q/k/v buf */

// ---------------- async global->LDS (16B) ----------------------------------
static __device__ __forceinline__ void gload16(const void* g, void* l) {
  __builtin_amdgcn_global_load_lds(
      (const __attribute__((address_space(1))) char*)(uintptr_t)g,
      (__attribute__((address_space(3))) char*)(uintptr_t)l,
      16, 0, 0);
}

static __device__ __forceinline__ uint packf16(float a, float b) {
  f16x2 h; h[0] = (f16)a; h[1] = (f16)b;
  return __builtin_bit_cast(uint, h);
}

// ---------------- fused fp32 -> fp16 convert (x, w_qkv, w_proj) -------------
// float4 index ranges: x [0,2097152), w_qkv [..,2883584), w_proj [..,3145728)
__global__ __launch_bounds__(256) void cvt_all(const float* __restrict__ x,
                                               const float* __restrict__ wq,
                                               const float* __restrict__ wp,
                                               f16* __restrict__ xh,
                                               f16* __restrict__ wqh,
                                               f16* __restrict__ wph) {
  const int i = blockIdx.x * 256 + threadIdx.x;
  const float* src; f16* dst; int j;
  if (i < 2097152)      { src = x;  dst = xh;  j = i; }
  else if (i < 2883584) { src = wq; dst = wqh; j = i - 2097152; }
  else                  { src = wp; dst = wph; j = i - 2883584; }
  float4 v = ((const float4*)src)[j];
  f16x4 h;
  h[0] = (f16)v.x; h[1] = (f16)v.y; h[2] = (f16)v.z; h[3] = (f16)v.w;
  *(f16x4*)(dst + (size_t)j * 4) = h;
}

// ---------------- GEMM C = A[M,1024] * Bt[NTOT,1024]^T + bias ---------------
// MODE 0: scatter q,k into [b][h][n][d] fp16 (outp); V third written DIRECTLY
//         transposed to vt [b][h][d][n] (outp2).
// MODE 1: C fp32 to outp ([row*NTOT + col])
template<int NTOT, int MODE>
__global__ __launch_bounds__(256, 2) void gemm_bt(const f16* __restrict__ A,
                                                  const f16* __restrict__ Bt,
                                                  const float* __restrict__ bias,
                                                  void* __restrict__ outp,
                                                  void* __restrict__ outp2) {
  __shared__ char smem[32768];
  const int t = threadIdx.x;
  const int w = t >> 6, lane = t & 63;
  const int lg = lane >> 4, lc = lane & 15;
  const int m0 = blockIdx.x * 128;
  const int n0 = blockIdx.y * 128;
  const int wr = w >> 1, wc = w & 1;

  f32x4 acc[4][4];
#pragma unroll
  for (int i = 0; i < 4; ++i)
#pragma unroll
    for (int j = 0; j < 4; ++j) acc[i][j] = (f32x4){0.f, 0.f, 0.f, 0.f};

  const char* Ab = (const char*)A + (size_t)m0 * 2048;
  const char* Bb = (const char*)Bt + (size_t)n0 * 2048;

  for (int k0 = 0; k0 < 1024; k0 += 64) {
#pragma unroll
    for (int f = 0; f < 4; ++f) {
      const int ci = f * 4 + w;
      const int x = ci * 1024 + lane * 16;
      const int row = x >> 7;
      const int col = (x & 127) ^ ((row & 7) << 4);
      gload16(Ab + (size_t)row * 2048 + k0 * 2 + col, smem + ci * 1024);
      gload16(Bb + (size_t)row * 2048 + k0 * 2 + col, smem + 16384 + ci * 1024);
    }
    __syncthreads();

#pragma unroll
    for (int kk = 0; kk < 2; ++kk) {
      f16x8 af[4], bf[4];
#pragma unroll
      for (int i = 0; i < 4; ++i) {
        const int ra = wr * 64 + i * 16 + lc;
        int ba = ra * 128 + kk * 64 + lg * 16;
        ba ^= (ra & 7) << 4;
        af[i] = *(const f16x8*)(smem + ba);
        const int rb = wc * 64 + i * 16 + lc;
        int bb = rb * 128 + kk * 64 + lg * 16;
        bb ^= (rb & 7) << 4;
        bf[i] = *(const f16x8*)(smem + 16384 + bb);
      }
#pragma unroll
      for (int i = 0; i < 4; ++i)
#pragma unroll
        for (int j = 0; j < 4; ++j)
          acc[i][j] = __builtin_amdgcn_mfma_f32_16x16x32_f16(af[i], bf[j], acc[i][j], 0, 0, 0);
    }
    __syncthreads();
  }

  float biasv[4];
#pragma unroll
  for (int j = 0; j < 4; ++j) biasv[j] = bias[n0 + wc * 64 + j * 16 + lc];

  if (MODE == 1) {
    float* Out = (float*)outp;
#pragma unroll
    for (int i = 0; i < 4; ++i)
#pragma unroll
      for (int j = 0; j < 4; ++j) {
        const int colL = n0 + wc * 64 + j * 16 + lc;
#pragma unroll
        for (int r = 0; r < 4; ++r) {
          const int row = m0 + wr * 64 + i * 16 + lg * 4 + r;
          Out[(size_t)row * NTOT + colL] = acc[i][j][r] + biasv[j];
        }
      }
  } else {
    f16* qk = (f16*)outp;     // q at +0, k at +BHND
    f16* vt = (f16*)outp2;    // [b][h][d][n]
#pragma unroll
    for (int i = 0; i < 4; ++i) {
      const int rbase = m0 + wr * 64 + i * 16 + lg * 4;
      const int bb = rbase >> 10, nb = rbase & 1023;   // 4 rows stay in one n-block
#pragma unroll
      for (int j = 0; j < 4; ++j) {
        const int colL = n0 + wc * 64 + j * 16 + lc;
        const int which = colL >> 10;                  // wave-uniform
        const int e = colL & 1023;
        const int h = e >> 6, d = e & 63;
        if (which == 2) {
          f16x4 vv;
#pragma unroll
          for (int r = 0; r < 4; ++r) vv[r] = (f16)(acc[i][j][r] + biasv[j]);
          *(f16x4*)(vt + ((size_t)(bb * NH + h) * HD + d) * SEQL + nb) = vv;
        } else {
#pragma unroll
          for (int r = 0; r < 4; ++r) {
            const int rr = rbase + r;
            const int b = rr >> 10, n = rr & 1023;
            qk[(size_t)which * BHND + ((size_t)(b * NH + h) * SEQL + n) * HD + d] =
                (f16)(acc[i][j][r] + biasv[j]);
          }
        }
      }
    }
  }
}

// ---------------- flash attention, swapped 32x32x16 MFMA --------------------
// EXACT round-10-verified body (59.4 us): single 16KB buffer, 2 barriers/tile,
// __expf, defer-max THR=8, permlane32_swap, XCD-local bh=bid&127. No setprio.
__global__ __launch_bounds__(256, 2) void attn_fwd(const f16* __restrict__ Q,
                                                   const f16* __restrict__ Kh,
                                                   const f16* __restrict__ Vt,
                                                   f16* __restrict__ Oh) {
  __shared__ uint4 Kl4[512];   // 8 KB: K tile [n=64][d=64] f16, XOR-swizzled
  __shared__ uint4 Vl4[512];   // 8 KB: Vt tile [d=64][n=64] f16, XOR-swizzled
  char* Kl = (char*)Kl4;
  char* Vl = (char*)Vl4;

  const int bid = blockIdx.x;
  const int bh = bid & 127;          // b*NH + h  (XCD-local: bid%8 == bh%8)
  const int qb = bid >> 7;
  const int t = threadIdx.x;
  const int w = t >> 6, lane = t & 63;
  const int l31 = lane & 31, hi = lane >> 5;

  const char* kbp = (const char*)Kh + (size_t)bh * 131072;   // SEQL*HD*2 bytes
  const char* vbp = (const char*)Vt + (size_t)bh * 131072;

  const f16* qp = Q + ((size_t)bh * SEQL + qb * 128 + w * 32 + l31) * HD;
  f16x8 qf[4];
#pragma unroll
  for (int dc = 0; dc < 4; ++dc) {
    f16x8 v = *(const f16x8*)(qp + dc * 16 + hi * 8);
#pragma unroll
    for (int e = 0; e < 8; ++e) v[e] = v[e] * (f16)0.125f;
    qf[dc] = v;
  }

  f32x16 acc0, acc1;
#pragma unroll
  for (int i = 0; i < 16; ++i) { acc0[i] = 0.f; acc1[i] = 0.f; }
  float m = -1e30f, l = 0.f;

  for (int kt = 0; kt < 16; ++kt) {
#pragma unroll
    for (int f = 0; f < 2; ++f) {
      const int ci = w * 2 + f;                 // wave-uniform chunk (1 KB)
      const int x = ci * 1024 + lane * 16;
      const int row = x >> 7;
      const int col = (x & 127) ^ ((row & 7) << 4);
      gload16(kbp + (size_t)(kt * 64 + row) * 128 + col, Kl + ci * 1024);
      gload16(vbp + (size_t)row * 2048 + kt * 128 + col, Vl + ci * 1024);
    }
    __syncthreads();

    // ---- S^T = K · Q ----
    f32x16 s0, s1;
#pragma unroll
    for (int i = 0; i < 16; ++i) { s0[i] = 0.f; s1[i] = 0.f; }
#pragma unroll
    for (int dc = 0; dc < 4; ++dc) {
      const int cb = dc * 32 + hi * 16;
      const int a0 = (l31 * 128 + cb) ^ ((l31 & 7) << 4);
      const int a1 = ((l31 + 32) * 128 + cb) ^ ((l31 & 7) << 4);
      f16x8 kf0 = *(const f16x8*)(Kl + a0);
      f16x8 kf1 = *(const f16x8*)(Kl + a1);
      s0 = __builtin_amdgcn_mfma_f32_32x32x16_f16(kf0, qf[dc], s0, 0, 0, 0);
      s1 = __builtin_amdgcn_mfma_f32_32x32x16_f16(kf1, qf[dc], s1, 0, 0, 0);
    }

    // ---- lane-local online softmax ----
    float v[32];
#pragma unroll
    for (int i = 0; i < 16; ++i) { v[i] = s0[i]; v[16 + i] = s1[i]; }
#pragma unroll
    for (int st = 16; st >= 1; st >>= 1)
#pragma unroll
      for (int i = 0; i < st; ++i) v[i] = fmaxf(v[i], v[i + st]);
    const float mx = fmaxf(v[0], __shfl_xor(v[0], 32));

    if (__any(mx > m + 8.f)) {
      const float nm = fmaxf(m, mx);
      const float al = __expf(m - nm);
      m = nm;
      l *= al;
      acc0 *= al;
      acc1 *= al;
    }

    float p[32];
#pragma unroll
    for (int i = 0; i < 16; ++i) {
      p[i] = __expf(s0[i] - m);
      p[16 + i] = __expf(s1[i] - m);
    }
    float ts[32];
#pragma unroll
    for (int i = 0; i < 32; ++i) ts[i] = p[i];
#pragma unroll
    for (int st = 16; st >= 1; st >>= 1)
#pragma unroll
      for (int i = 0; i < st; ++i) ts[i] += ts[i + st];
    const float rs = ts[0] + __shfl_xor(ts[0], 32);
    l += rs;

    uint wk[16];
#pragma unroll
    for (int i = 0; i < 16; ++i) wk[i] = packf16(p[2 * i], p[2 * i + 1]);

    // ---- O^T += Vt · P^T ----
#pragma unroll
    for (int ksub = 0; ksub < 2; ++ksub)
#pragma unroll
      for (int kh = 0; kh < 2; ++kh) {
        const int b0 = ksub * 8 + kh * 4;
        uintx2 r02 = __builtin_amdgcn_permlane32_swap(wk[b0 + 0], wk[b0 + 2], false, false);
        uintx2 r13 = __builtin_amdgcn_permlane32_swap(wk[b0 + 1], wk[b0 + 3], false, false);
        union { uint u[4]; f16x8 v; } fb;
        fb.u[0] = r02[0];
        fb.u[1] = r13[0];
        fb.u[2] = r02[1];
        fb.u[3] = r13[1];
        const int cb = ksub * 64 + kh * 32 + hi * 16;
        const int av0 = (l31 * 128 + cb) ^ ((l31 & 7) << 4);
        const int av1 = ((l31 + 32) * 128 + cb) ^ ((l31 & 7) << 4);
        f16x8 vf0 = *(const f16x8*)(Vl + av0);
        f16x8 vf1 = *(const f16x8*)(Vl + av1);
        acc0 = __builtin_amdgcn_mfma_f32_32x32x16_f16(vf0, fb.v, acc0, 0, 0, 0);
        acc1 = __builtin_amdgcn_mfma_f32_32x32x16_f16(vf1, fb.v, acc1, 0, 0, 0);
      }
    __syncthreads();
  }

  // ---- epilogue ----
  const int b = bh >> 4, h = bh & 15;
  const float inv = 1.f / l;
  f16* ob = Oh + ((size_t)(b * SEQL) + qb * 128 + w * 32 + l31) * EMB + h * 64;
#pragma unroll
  for (int g = 0; g < 4; ++g) {
    f16x4 o0, o1;
#pragma unroll
    for (int e = 0; e < 4; ++e) {
      o0[e] = (f16)(acc0[g * 4 + e] * inv);
      o1[e] = (f16)(acc1[g * 4 + e] * inv);
    }
    *(f16x4*)(ob + g * 8 + hi * 4) = o0;
    *(f16x4*)(ob + 32 + g * 8 + hi * 4) = o1;
  }
}

// ---------------- launcher --------------------------------------------------
extern "C" void kernel_launch(void* const* d_in, const int* in_sizes, int n_in,
                              void* d_out, int out_size, void* d_ws, size_t ws_size,
                              hipStream_t stream) {
  (void)in_sizes; (void)n_in; (void)out_size; (void)ws_size;
  const float* x      = (const float*)d_in[0];
  const float* w_qkv  = (const float*)d_in[1];
  const float* b_qkv  = (const float*)d_in[2];
  const float* w_proj = (const float*)d_in[3];
  const float* b_proj = (const float*)d_in[4];
  char* ws = (char*)d_ws;

  // workspace layout (72 MB, aliasing):
  const size_t XH = 0;                  // x fp16            16 MB (dead after gemm1)
  const size_t WQ = 16777216;           // w_qkv fp16         6 MB
  const size_t WP = 23068672;           // w_proj fp16        2 MB
  const size_t QH = 25165824;           // q [b][h][n][d]    16 MB
  const size_t KH = 41943040;           // k [b][h][n][d]    16 MB (QH + BHND*2)
  const size_t VT = 58720256;           // v^T [b][h][d][n]  16 MB (written by gemm1)
  const size_t AH = 0;                  // attn out [b][n][e] fp16 (aliases dead XH)

  f16* xh  = (f16*)(ws + XH);
  f16* wqh = (f16*)(ws + WQ);
  f16* wph = (f16*)(ws + WP);

  cvt_all<<<12288, 256, 0, stream>>>(x, w_qkv, w_proj, xh, wqh, wph);

  gemm_bt<3072, 0><<<dim3(64, 24), 256, 0, stream>>>(xh, wqh, b_qkv,
                                                     (void*)(ws + QH), (void*)(ws + VT));

  attn_fwd<<<NB * NH * 8, 256, 0, stream>>>((const f16*)(ws + QH),
                                            (const f16*)(ws + KH),
                                            (const f16*)(ws + VT),
                                            (f16*)(ws + AH));

  gemm_bt<1024, 1><<<dim3(64, 8), 256, 0, stream>>>((const f16*)(ws + AH), wph, b_proj,
                                                    d_out, nullptr);
}